// Round 11
// baseline (341.322 us; speedup 1.0000x reference)
//
#include <hip/hip_runtime.h>
#include <math.h>

// Problem constants
constexpr int Bn = 8, Tn = 32;
constexpr int D_INNER = 512;

typedef __attribute__((ext_vector_type(8))) short short8;   // 8 bf16
typedef __attribute__((ext_vector_type(8))) unsigned short ushort8;
typedef __attribute__((ext_vector_type(4))) float f32x4;

__device__ inline unsigned short f2bf(float x) {
    unsigned int u = __float_as_uint(x);
    unsigned int r = (u + 0x7FFF + ((u >> 16) & 1)) >> 16;  // RNE
    return (unsigned short)r;
}

// ---------------------------------------------------------------------------
// ONE prep kernel: conv bf16 weight packs + tail-weight transposes.
// ---------------------------------------------------------------------------
__global__ void prep_all(
    const float* __restrict__ cw0, const float* __restrict__ cw1,
    const float* __restrict__ cw2,
    const float* __restrict__ ip, const float* __restrict__ xp,
    const float* __restrict__ dt, const float* __restrict__ op,
    const float* __restrict__ h1, const float* __restrict__ h2,
    const float* __restrict__ ep, const float* __restrict__ bp2,
    const float* __restrict__ bp1,
    unsigned short* __restrict__ w0b, unsigned short* __restrict__ w1b,
    unsigned short* __restrict__ w2b, float* __restrict__ tW)
{
    int idx = blockIdx.x * blockDim.x + threadIdx.x;
    if (idx < 9216) {
        int d = idx;
        int sl = d & 7, sq = (d >> 3) & 3, co = (d >> 5) & 31;
        int r = d >> 10; int ky = r % 3, kt = r / 3;
        int q = sq ^ (co & 3) ^ ((co >> 2) & 3);
        float v = 0.f;
        if (q < 3 && sl < 3)
            v = cw0[((((size_t)co * 3 + sl) * 3 + kt) * 3 + ky) * 3 + q];
        w0b[d] = f2bf(v);
    } else if (idx < 64512) {
        int d = idx - 9216;
        int sl = d & 7, sg = (d >> 3) & 3, co = (d >> 5) & 63;
        int r = d >> 11; int k9 = r % 9, kt = r / 9;
        int ci = (sg ^ (co & 3)) * 8 + sl;
        w1b[d] = f2bf(cw1[((size_t)(co * 32 + ci) * 3 + kt) * 9 + k9]);
    } else if (idx < 230400) {
        int d = idx - 64512;
        int cip = d & 31; int rest = d >> 5;
        int co = rest % 96; rest /= 96;
        int k9 = rest % 9; int hh = rest / 9;
        int h = hh & 1, kt = hh >> 1;
        int ci = h * 32 + cip;
        w2b[d] = f2bf(cw2[((size_t)(co * 64 + ci) * 3 + kt) * 9 + k9]);
    } else if (idx < 730880) {
        int d = idx - 230400;
        const float* src; int N, K, base;
        if      (d < 262144) { src = ip;  N = 1024; K = 256; base = 0; }
        else if (d < 286720) { src = xp;  N = 48;   K = 512; base = 262144; }
        else if (d < 294912) { src = dt;  N = 512;  K = 16;  base = 286720; }
        else if (d < 425984) { src = op;  N = 256;  K = 512; base = 294912; }
        else if (d < 458752) { src = h1;  N = 128;  K = 256; base = 425984; }
        else if (d < 459264) { src = h2;  N = 4;    K = 128; base = 458752; }
        else if (d < 483840) { src = ep;  N = 256;  K = 96;  base = 459264; }
        else if (d < 500224) { src = bp2; N = 256;  K = 64;  base = 483840; }
        else                 { src = bp1; N = 64;   K = 4;   base = 500224; }
        int s = d - base;
        int o = s / K, k = s - o * K;
        tW[base + k * N + o] = src[s];
    }
}

// ---------------------------------------------------------------------------
// Stage 0 as MFMA implicit GEMM, T-CHUNKED with 4-slot LDS plane ring.
// Block = (b, yt, xh, tc): 8 consecutive t. Planes ts in [8tc-1, 8tc+8] fill
// the ring once each (vs 3x in the per-t version). One barrier per t.
// slot(ts) = (ts - (8tc-1)) & 3. Iter i (t=8tc+i): compute reads slots
// i,i+1,i+2 (&3); prefetch plane t+2 writes slot (i+3)&3 — disjoint.
// 8 waves = pyp(4) x hx(2); acc[2 dy][2 nt] per t; epilogue per t.
// LDS: 4 x 18496 (ring) + 18432 (W) = 92416 B -> 1 block/CU.
// ---------------------------------------------------------------------------
constexpr int C0_STR  = 68;
constexpr int C0_BLKS = 17 * C0_STR;         // 1156 16B-blocks per plane slice

__device__ inline void conv0_fill(unsigned short* dst, const float* __restrict__ in,
                                  int b, int ts, int yt, int xh, int tid)
{
    bool tok = (ts >= 0 && ts < Tn);
    const float* src = in + (size_t)(b * Tn + (tok ? ts : 0)) * 3 * 16384;
    for (int e = tid; e < C0_BLKS; e += 512) {
        int r = e / C0_STR, c = e - r * C0_STR;
        int gy = 16 * yt - 1 + r;
        int x  = 64 * xh + c - 1;
        bool ok = tok && gy >= 0 && gy < 128 && x >= 0 && x < 128;
        float v0 = 0.f, v1 = 0.f, v2 = 0.f;
        if (ok) {
            const float* p = src + gy * 128 + x;
            v0 = p[0]; v1 = p[16384]; v2 = p[32768];
        }
        ushort8 pk = (ushort8)0;
        pk[0] = f2bf(v0); pk[1] = f2bf(v1); pk[2] = f2bf(v2);
        *(ushort8*)(dst + (size_t)e * 8) = pk;
    }
}

__global__ __launch_bounds__(512) void conv0_kernel(
    const float* __restrict__ in, const unsigned short* __restrict__ w0b,
    const float* __restrict__ bias, const float* __restrict__ gam,
    const float* __restrict__ bet, unsigned short* __restrict__ out)
{
    int tid  = threadIdx.x;
    int lane = tid & 63;
    int wv   = __builtin_amdgcn_readfirstlane(tid >> 6);  // wave 0..7
    int q    = lane >> 4;
    int l15  = lane & 15;
    int pyp  = wv >> 1;
    int hx   = wv & 1;
    int bI = blockIdx.x;                  // b(8) x yt(8) x xh(2) x tc(4) = 512
    int b  = bI >> 6;
    int yt = (bI >> 3) & 7;
    int xh = (bI >> 2) & 1;
    int tc = bI & 3;
    int tbase = 8 * tc;

    __shared__ __align__(16) unsigned short S[4][C0_BLKS * 8];  // 4 x 18496 B
    __shared__ __align__(16) unsigned short W[9 * 32 * 32];     // 18432 B

    // stage all weights + first 3 planes (ts = tbase-1, tbase, tbase+1)
    {
        const uint4* wsrc = (const uint4*)w0b;
        uint4* wdst = (uint4*)W;
        for (int e = tid; e < 1152; e += 512) wdst[e] = wsrc[e];
    }
    conv0_fill(S[0], in, b, tbase - 1, yt, xh, tid);
    conv0_fill(S[1], in, b, tbase,     yt, xh, tid);
    conv0_fill(S[2], in, b, tbase + 1, yt, xh, tid);
    __syncthreads();

    int oxl = hx * 16 + l15;              // 0..31 within x-half

    for (int i = 0; i < 8; ++i) {
        int t = tbase + i;
        if (i < 7) conv0_fill(S[(i + 3) & 3], in, b, t + 2, yt, xh, tid);

        f32x4 acc[2][2];
        #pragma unroll
        for (int dy = 0; dy < 2; ++dy)
            #pragma unroll
            for (int nt = 0; nt < 2; ++nt) acc[dy][nt] = (f32x4)0.f;

        #pragma unroll
        for (int kt = 0; kt < 3; ++kt) {
            const unsigned short* Sb = S[(i + kt) & 3];
            #pragma unroll
            for (int ky = 0; ky < 3; ++ky) {
                short8 bfr[2];
                #pragma unroll
                for (int nt = 0; nt < 2; ++nt) {
                    int co = nt * 16 + l15;
                    int i16 = ((kt * 3 + ky) * 32 + co) * 4 +
                              (q ^ (co & 3) ^ ((co >> 2) & 3));
                    bfr[nt] = *(const short8*)(W + (size_t)i16 * 8);
                }
                #pragma unroll
                for (int dy = 0; dy < 2; ++dy) {
                    int r = 4 * pyp + 2 * dy + ky;
                    short8 af = (short8)0;
                    if (q < 3)
                        af = *(const short8*)(Sb + (size_t)(r * C0_STR + 2 * oxl + q) * 8);
                    #pragma unroll
                    for (int nt = 0; nt < 2; ++nt)
                        acc[dy][nt] = __builtin_amdgcn_mfma_f32_16x16x32_bf16(
                            af, bfr[nt], acc[dy][nt], 0, 0, 0);
                }
            }
        }

        // epilogue for this t: BN + ReLU + maxpool(2,2); store bf16 [y][x][ci]
        unsigned short* dst = out + (size_t)(b * Tn + t) * 32768;
        #pragma unroll
        for (int nt = 0; nt < 2; ++nt) {
            int co = nt * 16 + l15;
            float bi = bias[co], g = gam[co], be = bet[co];
            #pragma unroll
            for (int j = 0; j < 2; ++j) {
                float m0 = fmaxf(fmaf(g, acc[0][nt][2 * j]     + bi, be), 0.f);
                float m1 = fmaxf(fmaf(g, acc[0][nt][2 * j + 1] + bi, be), 0.f);
                float m2 = fmaxf(fmaf(g, acc[1][nt][2 * j]     + bi, be), 0.f);
                float m3 = fmaxf(fmaf(g, acc[1][nt][2 * j + 1] + bi, be), 0.f);
                float p = fmaxf(fmaxf(m0, m1), fmaxf(m2, m3));
                int pox = xh * 16 + hx * 8 + q * 2 + j;
                int poy = yt * 4 + pyp;
                dst[(poy * 32 + pox) * 32 + co] = f2bf(p);
            }
        }
        __syncthreads();    // ring slot (i+3)&3 ready; old readers done
    }
}

// ---------------------------------------------------------------------------
// Stage 1 as MFMA implicit GEMM, y-half split (verified round 9).
// ---------------------------------------------------------------------------
__global__ __launch_bounds__(512) void conv1_kernel(
    const unsigned short* __restrict__ in, const unsigned short* __restrict__ w1b,
    const float* __restrict__ bias, const float* __restrict__ gam,
    const float* __restrict__ bet, unsigned short* __restrict__ out)
{
    int tid  = threadIdx.x;
    int lane = tid & 63;
    int wv   = tid >> 6;
    int q    = lane >> 4;
    int l15  = lane & 15;
    int oyp  = wv >> 1;
    int nh   = wv & 1;
    int bt = blockIdx.x >> 1, half = blockIdx.x & 1;
    int b = bt >> 5, t = bt & 31;

    __shared__ __align__(16) unsigned short S[17 * 34 * 32];
    __shared__ __align__(16) unsigned short W[9 * 64 * 32];

    f32x4 acc[2][2];
    #pragma unroll
    for (int mt = 0; mt < 2; ++mt)
        #pragma unroll
        for (int nt = 0; nt < 2; ++nt) acc[mt][nt] = (f32x4)0.f;

    for (int kt = 0; kt < 3; ++kt) {
        int ts = t + kt - 1;
        if (ts < 0 || ts >= Tn) continue;
        __syncthreads();
        const unsigned short* src = in + (size_t)(b * Tn + ts) * 32768;
        for (int e = tid; e < 17 * 34 * 4; e += 512) {
            int sb = e & 3;
            int pos = e >> 2;
            int ys = pos / 34, xs = pos - ys * 34;
            int g = sb ^ ((xs >> 1) & 3);
            int y = 16 * half + ys - 1, x = xs - 1;
            ushort8 v = (ushort8)0;
            if (y >= 0 && x >= 0 && x < 32)
                v = *(const ushort8*)(src + ((y * 32 + x) * 32 + g * 8));
            *(ushort8*)(S + (size_t)e * 8) = v;
        }
        {
            const uint4* wsrc = (const uint4*)(w1b + kt * 18432);
            uint4* wdst = (uint4*)W;
            for (int e = tid; e < 2304; e += 512) wdst[e] = wsrc[e];
        }
        __syncthreads();

        for (int k9 = 0; k9 < 9; ++k9) {
            int ky = k9 / 3, kx = k9 - ky * 3;
            short8 bf[2];
            #pragma unroll
            for (int nt = 0; nt < 2; ++nt) {
                int co = nh * 32 + nt * 16 + l15;
                int blk = (k9 * 64 + co) * 4 + (q ^ (co & 3));
                bf[nt] = *(const short8*)(W + blk * 8);
            }
            short8 af[2];
            #pragma unroll
            for (int mt = 0; mt < 2; ++mt) {
                int oyl = 2 * oyp + mt;
                int ys = 2 * oyl + ky;
                int xs = 2 * l15 + kx;
                int blk = (ys * 34 + xs) * 4 + (q ^ ((xs >> 1) & 3));
                af[mt] = *(const short8*)(S + blk * 8);
            }
            #pragma unroll
            for (int mt = 0; mt < 2; ++mt)
                #pragma unroll
                for (int nt = 0; nt < 2; ++nt)
                    acc[mt][nt] = __builtin_amdgcn_mfma_f32_16x16x32_bf16(
                        af[mt], bf[nt], acc[mt][nt], 0, 0, 0);
        }
    }

    unsigned short* dst = out + (size_t)bt * 4096;
    #pragma unroll
    for (int nt = 0; nt < 2; ++nt) {
        int co = nh * 32 + nt * 16 + l15;
        float bi = bias[co], g = gam[co], be = bet[co];
        #pragma unroll
        for (int j = 0; j < 2; ++j) {
            float m0 = fmaxf(fmaf(g, acc[0][nt][2 * j]     + bi, be), 0.f);
            float m1 = fmaxf(fmaf(g, acc[0][nt][2 * j + 1] + bi, be), 0.f);
            float m2 = fmaxf(fmaf(g, acc[1][nt][2 * j]     + bi, be), 0.f);
            float m3 = fmaxf(fmaf(g, acc[1][nt][2 * j + 1] + bi, be), 0.f);
            float p = fmaxf(fmaxf(m0, m1), fmaxf(m2, m3));
            int px = 2 * q + j, py = half * 4 + oyp;
            dst[(py * 8 + px) * 64 + co] = f2bf(p);
        }
    }
}

// ---------------------------------------------------------------------------
// Stage 2 as MFMA implicit GEMM. Epilogue now ALSO reduces the 2x2 pooled
// tile to its mean and writes gap[96] per token (buf2 eliminated — GAP is
// its only consumer).
// ---------------------------------------------------------------------------
__global__ __launch_bounds__(384) void conv2_kernel(
    const unsigned short* __restrict__ in, const unsigned short* __restrict__ w2b,
    const float* __restrict__ bias, const float* __restrict__ gam,
    const float* __restrict__ bet, float* __restrict__ gapb)
{
    int tid  = threadIdx.x;
    int lane = tid & 63;
    int wv   = tid >> 6;
    int q    = lane >> 4;
    int l15  = lane & 15;
    int bt = blockIdx.x;
    int b = bt >> 5, t = bt & 31;

    __shared__ __align__(16) unsigned short W[864 * 5 * 8];
    __shared__ __align__(16) unsigned short S[81 * 5 * 8];

    f32x4 acc = (f32x4)0.f;

    for (int kt = 0; kt < 3; ++kt) {
        int ts = t + kt - 1;
        if (ts < 0 || ts >= Tn) continue;
        for (int h = 0; h < 2; ++h) {
            __syncthreads();
            const unsigned short* wsrc = w2b + (size_t)((kt * 2 + h) * 9) * 96 * 32;
            for (int e = tid; e < 3456; e += 384) {
                int r = e >> 2, qq = e & 3;
                uint4 v = *(const uint4*)(wsrc + r * 32 + qq * 8);
                *(uint4*)(W + (r * 5 + qq) * 8) = v;
            }
            const unsigned short* src = in + (size_t)(b * Tn + ts) * 4096 + h * 32;
            for (int e = tid; e < 81 * 4; e += 384) {
                int cb = e & 3, p = e >> 2;
                int ys = p / 9, xs = p - ys * 9;
                int y = ys - 1, x = xs - 1;
                ushort8 v = (ushort8)0;
                if (y >= 0 && x >= 0 && y < 8 && x < 8)
                    v = *(const ushort8*)(src + ((y * 8 + x) * 64 + cb * 8));
                *(ushort8*)(S + (size_t)(p * 5 + cb) * 8) = v;
            }
            __syncthreads();

            int oy = l15 >> 2, ox = l15 & 3;
            #pragma unroll
            for (int k9 = 0; k9 < 9; ++k9) {
                int ky = k9 / 3, kx = k9 - ky * 3;
                short8 bf = *(const short8*)(W + (size_t)((k9 * 96 + wv * 16 + l15) * 5 + q) * 8);
                int p = (2 * oy + ky) * 9 + (2 * ox + kx);
                short8 af = *(const short8*)(S + (size_t)(p * 5 + q) * 8);
                acc = __builtin_amdgcn_mfma_f32_16x16x32_bf16(af, bf, acc, 0, 0, 0);
            }
        }
    }

    int co = wv * 16 + l15;
    float bi = bias[co], g = gam[co], be = bet[co];
    float v0 = fmaxf(fmaf(g, acc[0] + bi, be), 0.f);
    float v1 = fmaxf(fmaf(g, acc[1] + bi, be), 0.f);
    float v2 = fmaxf(fmaf(g, acc[2] + bi, be), 0.f);
    float v3 = fmaxf(fmaf(g, acc[3] + bi, be), 0.f);
    float p0 = fmaxf(v0, v1);
    float p1 = fmaxf(v2, v3);
    float r0 = fmaxf(p0, __shfl_xor(p0, 16));   // pooled (py=q>>1, px=0)
    float r1 = fmaxf(p1, __shfl_xor(p1, 16));   // pooled (py=q>>1, px=1)
    float gsum = r0 + r1;                        // row-sum, valid q=0 and q=2
    gsum += __shfl_xor(gsum, 32);                // combine py rows (q0<->q2)
    if (q == 0) gapb[(size_t)bt * 96 + co] = 0.25f * gsum;
}

// ---------------------------------------------------------------------------
// FUSED: gap + ep proj + bbox MLP -> u (LDS) -> in_proj -> xz.
// ---------------------------------------------------------------------------
__global__ __launch_bounds__(256) void fuse_u_inproj(
    const float* __restrict__ gapb, const float* __restrict__ epT,
    const float* __restrict__ ep_b, const float* __restrict__ bb,
    const float* __restrict__ bp1T, const float* __restrict__ bp1_b,
    const float* __restrict__ bp2T, const float* __restrict__ bp2_b,
    const float* __restrict__ ipwT, float* __restrict__ xzb)
{
    int bt = blockIdx.x;
    int m  = threadIdx.x;
    __shared__ float hs[64];
    __shared__ float gap[96];
    __shared__ float u_lds[256];
    if (m < 64) {
        float a = bp1_b[m];
        #pragma unroll
        for (int k = 0; k < 4; ++k) a = fmaf(bp1T[k * 64 + m], bb[bt * 4 + k], a);
        hs[m] = fmaxf(a, 0.f);
    } else if (m < 160) {
        gap[m - 64] = gapb[(size_t)bt * 96 + (m - 64)];
    }
    __syncthreads();
    float ff = ep_b[m];
    for (int c = 0; c < 96; ++c) ff = fmaf(gap[c], epT[c * 256 + m], ff);
    float bfv = bp2_b[m];
    for (int j = 0; j < 64; ++j) bfv = fmaf(hs[j], bp2T[j * 256 + m], bfv);
    u_lds[m] = ff + bfv;
    __syncthreads();

    const float4* wbase = (const float4*)ipwT + m;
    float4 acc = {0.f, 0.f, 0.f, 0.f};
    for (int k = 0; k < 256; ++k) {
        float uk = u_lds[k];
        float4 w4 = wbase[(size_t)k * 256];
        acc.x = fmaf(uk, w4.x, acc.x);
        acc.y = fmaf(uk, w4.y, acc.y);
        acc.z = fmaf(uk, w4.z, acc.z);
        acc.w = fmaf(uk, w4.w, acc.w);
    }
    *(float4*)(xzb + (size_t)bt * 1024 + 4 * m) = acc;
}

// ---------------------------------------------------------------------------
// FUSED: conv1d+silu -> x_proj -> dt_proj(softplus).
// ---------------------------------------------------------------------------
__global__ __launch_bounds__(512) void convxd_kernel(
    const float* __restrict__ xzb, const float* __restrict__ c1w,
    const float* __restrict__ c1b, const float* __restrict__ xpw,
    const float* __restrict__ dtwT, const float* __restrict__ dt_b,
    float* __restrict__ xsb, float* __restrict__ xdb, float* __restrict__ dtbf)
{
    int bt = blockIdx.x;
    int b = bt >> 5, t = bt & 31;
    int tid = threadIdx.x;
    __shared__ float xs_lds[512];
    __shared__ float xd_lds[48];

    {
        float acc = c1b[tid];
        #pragma unroll
        for (int k = 0; k < 4; ++k) {
            int ts = t - 3 + k;
            if (ts >= 0)
                acc = fmaf(c1w[tid * 4 + k], xzb[(size_t)(b * Tn + ts) * 1024 + tid], acc);
        }
        float v = acc / (1.f + expf(-acc));
        xs_lds[tid] = v;
        xsb[(size_t)bt * 512 + tid] = v;
    }
    __syncthreads();

    {
        int wv = tid >> 6, ln = tid & 63;
        #pragma unroll
        for (int u = 0; u < 6; ++u) {
            int o = wv * 6 + u;
            const float* wrow = xpw + (size_t)o * 512;
            float acc = 0.f;
            #pragma unroll
            for (int e = 0; e < 8; ++e)
                acc = fmaf(wrow[ln + 64 * e], xs_lds[ln + 64 * e], acc);
            acc += __shfl_xor(acc, 32); acc += __shfl_xor(acc, 16);
            acc += __shfl_xor(acc, 8);  acc += __shfl_xor(acc, 4);
            acc += __shfl_xor(acc, 2);  acc += __shfl_xor(acc, 1);
            if (ln == 0) {
                xd_lds[o] = acc;
                xdb[(size_t)bt * 48 + o] = acc;
            }
        }
    }
    __syncthreads();

    {
        float a = dt_b[tid];
        #pragma unroll
        for (int k = 0; k < 16; ++k) a = fmaf(xd_lds[k], dtwT[k * 512 + tid], a);
        a = (a > 20.f) ? a : log1pf(expf(a));
        dtbf[(size_t)bt * 512 + tid] = a;
    }
}

// ---------------------------------------------------------------------------
// Wave-parallel selective scan.
// ---------------------------------------------------------------------------
__global__ __launch_bounds__(256) void ssm_kernel(
    const float* __restrict__ xdbl, const float* __restrict__ dtb,
    const float* __restrict__ xs, const float* __restrict__ xz,
    const float* __restrict__ A_log, const float* __restrict__ Dp,
    float* __restrict__ y)
{
    int tid = threadIdx.x;
    int lane = tid & 63;
    int s = lane & 15, dsub = lane >> 4;
    int gid = blockIdx.x * 4 + (tid >> 6);
    int b = gid >> 7;
    int d = ((gid & 127) << 2) + dsub;

    float A = -expf(A_log[d * 16 + s]);
    float Dv = Dp[d];
    float h = 0.f;
    for (int t = 0; t < Tn; ++t) {
        int bt = b * Tn + t;
        float dtv = dtb[(size_t)bt * 512 + d];
        float xv  = xs [(size_t)bt * 512 + d];
        float Bs  = xdbl[(size_t)bt * 48 + 16 + s];
        float Cs  = xdbl[(size_t)bt * 48 + 32 + s];
        float dA = expf(dtv * A);
        h = fmaf(dA, h, dtv * Bs * xv);
        float c = h * Cs;
        c += __shfl_xor(c, 8, 16);
        c += __shfl_xor(c, 4, 16);
        c += __shfl_xor(c, 2, 16);
        c += __shfl_xor(c, 1, 16);
        if (s == 0) {
            float zv = xz[(size_t)bt * 1024 + 512 + d];
            float sig = 1.f / (1.f + expf(-zv));
            y[(size_t)bt * 512 + d] = (c + Dv * xv) * (zv * sig);
        }
    }
}

// ---------------------------------------------------------------------------
// FUSED: out_proj -> h1(relu) -> h2(sigmoid) -> meas.
// ---------------------------------------------------------------------------
__global__ __launch_bounds__(256) void out_head_kernel(
    const float* __restrict__ yb, const float* __restrict__ opwT,
    const float* __restrict__ h1wT, const float* __restrict__ h1_b,
    const float* __restrict__ h2w, const float* __restrict__ h2_b,
    float* __restrict__ meas_out)
{
    int bt = blockIdx.x;
    int m  = threadIdx.x;
    __shared__ float y_lds[512];
    __shared__ float mo_lds[256];
    __shared__ float hid_lds[128];

    y_lds[m]       = yb[(size_t)bt * 512 + m];
    y_lds[m + 256] = yb[(size_t)bt * 512 + m + 256];
    __syncthreads();

    {
        float a = 0.f;
        for (int k = 0; k < 512; ++k) a = fmaf(y_lds[k], opwT[k * 256 + m], a);
        mo_lds[m] = a;
    }
    __syncthreads();

    if (m < 128) {
        float a = h1_b[m];
        for (int k = 0; k < 256; ++k) a = fmaf(mo_lds[k], h1wT[k * 128 + m], a);
        hid_lds[m] = fmaxf(a, 0.f);
    }
    __syncthreads();

    if (m < 64) {
        int o2 = m >> 4, l15 = m & 15;
        float acc = 0.f;
        #pragma unroll
        for (int e = 0; e < 8; ++e)
            acc = fmaf(h2w[o2 * 128 + l15 + 16 * e], hid_lds[l15 + 16 * e], acc);
        acc += __shfl_xor(acc, 8, 16);
        acc += __shfl_xor(acc, 4, 16);
        acc += __shfl_xor(acc, 2, 16);
        acc += __shfl_xor(acc, 1, 16);
        if (l15 == 0) {
            float a = acc + h2_b[o2];
            meas_out[bt * 4 + o2] = 1.f / (1.f + expf(-a));
        }
    }
}

// ---------------------------------------------------------------------------
// Wave-parallel Kalman filter (verified round 10).
// ---------------------------------------------------------------------------
__device__ __forceinline__ float kf_mm(float Av, float Bv, int i, int j, int gb) {
    float c = 0.f;
    #pragma unroll
    for (int k = 0; k < 4; ++k)
        c = fmaf(__shfl(Av, gb + i * 4 + k, 64), __shfl(Bv, gb + k * 4 + j, 64), c);
    return c;
}
__device__ __forceinline__ float kf_mmT(float Av, float Bv, int i, int j, int gb) {
    float c = 0.f;
    #pragma unroll
    for (int k = 0; k < 4; ++k)
        c = fmaf(__shfl(Av, gb + i * 4 + k, 64), __shfl(Bv, gb + j * 4 + k, 64), c);
    return c;
}

__global__ __launch_bounds__(128) void kf_kernel(
    const float* __restrict__ meas, const float* __restrict__ bb,
    const float* __restrict__ Fin, const float* __restrict__ Hmin,
    const float* __restrict__ lq, const float* __restrict__ lr,
    float* __restrict__ pred)
{
    int tid = threadIdx.x;
    int b   = tid >> 4;
    int l16 = tid & 15;
    int i = l16 >> 2, j = l16 & 3;
    int gb = tid & 48;

    float Fv = Fin[l16], Hv = Hmin[l16];
    float R4[4];
    #pragma unroll
    for (int k = 0; k < 4; ++k) R4[k] = expf(lr[k]) + 1e-6f;
    float qi = expf(lq[i]) + 1e-6f;

    float sv = bb[b * 128 + j];
    float Pv = (i == j) ? 0.01f : 0.f;

    for (int t = 0; t < Tn; ++t) {
        float mv = meas[(b * Tn + t) * 4 + j];
        float tr = Fv * sv;
        tr += __shfl_xor(tr, 1); tr += __shfl_xor(tr, 2);
        float spv = tr;
        float spj = __shfl(spv, gb + j * 4, 64);
        float FPv = kf_mm(Fv, Pv, i, j, gb);
        float Ppv = kf_mmT(FPv, Fv, i, j, gb) + ((i == j) ? qi : 0.f);
        float hsp = Hv * spj;
        hsp += __shfl_xor(hsp, 1); hsp += __shfl_xor(hsp, 2);
        float yrv = mv - __shfl(hsp, gb + j * 4, 64);
        float HPv = kf_mm(Hv, Ppv, i, j, gb);
        float Sv = kf_mmT(HPv, Hv, i, j, gb) + ((i == j) ? R4[i] : 0.f);
        float Xv = Hv;
        #pragma unroll
        for (int c = 0; c < 4; ++c) {
            float piv = __shfl(Sv, gb + c * 5, 64);
            float dinv = 1.f / piv;
            if (i == c) { Sv *= dinv; Xv *= dinv; }
            float Scj = __shfl(Sv, gb + c * 4 + j, 64);
            float Xcj = __shfl(Xv, gb + c * 4 + j, 64);
            float f = __shfl(Sv, gb + i * 4 + c, 64);
            if (i != c) { Sv = fmaf(-f, Scj, Sv); Xv = fmaf(-f, Xcj, Xv); }
        }
        float Kv = kf_mmT(Ppv, Xv, i, j, gb);
        float t3 = Kv * yrv;
        t3 += __shfl_xor(t3, 1); t3 += __shfl_xor(t3, 2);
        float snv = spv + t3;
        if (j == 0) pred[(b * Tn + t) * 4 + i] = snv;
        float IKHv = ((i == j) ? 1.f : 0.f) - kf_mm(Kv, Hv, i, j, gb);
        float T1v = kf_mm(IKHv, Ppv, i, j, gb);
        float krk = 0.f;
        #pragma unroll
        for (int k = 0; k < 4; ++k)
            krk = fmaf(__shfl(Kv, gb + i * 4 + k, 64) * R4[k],
                       __shfl(Kv, gb + j * 4 + k, 64), krk);
        Pv = kf_mmT(T1v, IKHv, i, j, gb) + krk;
        sv = __shfl(snv, gb + j * 4, 64);
    }
}

// ---------------------------------------------------------------------------
extern "C" void kernel_launch(void* const* d_in, const int* in_sizes, int n_in,
                              void* d_out, int out_size, void* d_ws, size_t ws_size,
                              hipStream_t stream)
{
    const float* frames = (const float*)d_in[0];
    const float* bb     = (const float*)d_in[1];
    const float* cw0 = (const float*)d_in[2],  *cb0 = (const float*)d_in[3];
    const float* g0  = (const float*)d_in[4],  *be0 = (const float*)d_in[5];
    const float* cw1 = (const float*)d_in[6],  *cb1 = (const float*)d_in[7];
    const float* g1  = (const float*)d_in[8],  *be1 = (const float*)d_in[9];
    const float* cw2 = (const float*)d_in[10], *cb2 = (const float*)d_in[11];
    const float* g2  = (const float*)d_in[12], *be2 = (const float*)d_in[13];
    const float* ep_w  = (const float*)d_in[14], *ep_b  = (const float*)d_in[15];
    const float* bp1_w = (const float*)d_in[16], *bp1_b = (const float*)d_in[17];
    const float* bp2_w = (const float*)d_in[18], *bp2_b = (const float*)d_in[19];
    const float* in_proj_w = (const float*)d_in[20];
    const float* c1w = (const float*)d_in[21], *c1b = (const float*)d_in[22];
    const float* x_proj_w = (const float*)d_in[23];
    const float* dt_w = (const float*)d_in[24], *dt_b = (const float*)d_in[25];
    const float* A_log = (const float*)d_in[26], *Dp = (const float*)d_in[27];
    const float* out_proj_w = (const float*)d_in[28];
    const float* h1_w = (const float*)d_in[29], *h1_b = (const float*)d_in[30];
    const float* h2_w = (const float*)d_in[31], *h2_b = (const float*)d_in[32];
    const float* kfF = (const float*)d_in[33], *kfH = (const float*)d_in[34];
    const float* kfq = (const float*)d_in[35], *kfr = (const float*)d_in[36];

    // workspace layout
    float* ws   = (float*)d_ws;
    float* gapb = ws;                        // (256,96)       24576
    float* xzb  = gapb + 24576;              // (256,1024)    262144
    float* xsb  = xzb  + 262144;             // (256,512)     131072
    float* xdb  = xsb  + 131072;             // (256,48)       12288
    float* dtbf = xdb  + 12288;              // (256,512)     131072
    float* yb   = dtbf + 131072;             // (256,512)     131072
    float* tW   = yb   + 131072;             // transposed weights 500480
    unsigned short* buf0b = (unsigned short*)(tW + 500480);  // bf16 (256,32,32,32)
    unsigned short* buf1b = buf0b + 8388608;                 // bf16 (256,8,8,64)
    unsigned short* w2b   = buf1b + 131072;
    unsigned short* w1b   = w2b + 165888;
    unsigned short* w0b   = w1b + 55296;

    float* ipwT = tW;
    float* dtwT = tW + 286720;
    float* opwT = tW + 294912;
    float* h1wT = tW + 425984;
    float* epwT = tW + 459264;
    float* bp2T = tW + 483840;
    float* bp1T = tW + 500224;

    float* kf_out   = (float*)d_out;          // (8,32,4)
    float* meas_out = kf_out + Bn * Tn * 4;   // (8,32,4)

    auto nblk = [](int n) { return dim3((unsigned)((n + 255) / 256)); };

    prep_all<<<nblk(730880), 256, 0, stream>>>(cw0, cw1, cw2,
                                               in_proj_w, x_proj_w, dt_w, out_proj_w,
                                               h1_w, h2_w, ep_w, bp2_w, bp1_w,
                                               w0b, w1b, w2b, tW);

    conv0_kernel<<<dim3(512), 512, 0, stream>>>(frames, w0b, cb0, g0, be0, buf0b);
    conv1_kernel<<<dim3(512), 512, 0, stream>>>(buf0b, w1b, cb1, g1, be1, buf1b);
    conv2_kernel<<<dim3(256), 384, 0, stream>>>(buf1b, w2b, cb2, g2, be2, gapb);

    fuse_u_inproj<<<dim3(256), 256, 0, stream>>>(gapb, epwT, ep_b, bb, bp1T, bp1_b,
                                                 bp2T, bp2_b, ipwT, xzb);
    convxd_kernel<<<dim3(256), 512, 0, stream>>>(xzb, c1w, c1b, x_proj_w,
                                                 dtwT, dt_b, xsb, xdb, dtbf);
    ssm_kernel<<<dim3(256), 256, 0, stream>>>(xdb, dtbf, xsb, xzb, A_log, Dp, yb);
    out_head_kernel<<<dim3(256), 256, 0, stream>>>(yb, opwT, h1wT, h1_b,
                                                   h2_w, h2_b, meas_out);
    kf_kernel<<<dim3(1), 128, 0, stream>>>(meas_out, bb, kfF, kfH, kfq, kfr, kf_out);
}